// Round 5
// baseline (927.496 us; speedup 1.0000x reference)
//
#include <hip/hip_runtime.h>

#define N_NODES 100000
#define N_EDGES 1600000
#define D_IN    256
#define D_HID   64
#define D_OUT   40
#define PROP_N  16
#define COL_SPLIT 50000u

typedef short short8 __attribute__((ext_vector_type(8)));   // 8 bf16 (4 VGPRs)
typedef float f32x4  __attribute__((ext_vector_type(4)));   // MFMA accumulator

// ---- fp8 (OCP e4m3) helpers: HW convert, RNE, saturating ------------------
__device__ __forceinline__ unsigned char f32_to_fp8(float f) {
    int p = __builtin_amdgcn_cvt_pk_fp8_f32(f, f, 0, false);
    return (unsigned char)(p & 0xff);
}
// ---- bf16 helpers (RNE) ---------------------------------------------------
__device__ __forceinline__ unsigned short f32_to_bf16(float f) {
    unsigned int u = __float_as_uint(f);
    unsigned int r = (u + 0x7fffu + ((u >> 16) & 1u)) >> 16;
    return (unsigned short)r;
}
__device__ __forceinline__ unsigned int f32x2_to_bf16x2(float lo, float hi) {
    return (unsigned int)f32_to_bf16(lo) | ((unsigned int)f32_to_bf16(hi) << 16);
}
__device__ __forceinline__ float bf16_f(unsigned short u) {
    return __uint_as_float(((unsigned)u) << 16);
}
// decode packed edge: bits[31:15]=col, bits[14:0]=bf16(val) without sign
__device__ __forceinline__ float edge_val(unsigned p) {
    return __uint_as_float((p & 0x7fffu) << 16);
}
// 4-feature fp8 FMA: b holds 4 fp8 bytes
__device__ __forceinline__ void fma4(float4& a, float v, unsigned b) {
    a.x = fmaf(v, __builtin_amdgcn_cvt_f32_fp8((int)b, 0), a.x);
    a.y = fmaf(v, __builtin_amdgcn_cvt_f32_fp8((int)b, 1), a.y);
    a.z = fmaf(v, __builtin_amdgcn_cvt_f32_fp8((int)b, 2), a.z);
    a.w = fmaf(v, __builtin_amdgcn_cvt_f32_fp8((int)b, 3), a.w);
}

// ---------------------------------------------------------------------------
// Kernel 1: CSR row_ptr from sorted edge_row via binary search.
// ---------------------------------------------------------------------------
__global__ __launch_bounds__(256) void build_rowptr(const int* __restrict__ erow,
                                                    int* __restrict__ rp) {
    int r = blockIdx.x * blockDim.x + threadIdx.x;
    if (r > N_NODES) return;
    int lo = 0, hi = N_EDGES;
    while (lo < hi) {
        int mid = (lo + hi) >> 1;
        if (erow[mid] < r) lo = mid + 1; else hi = mid;
    }
    rp[r] = lo;
}

// ---------------------------------------------------------------------------
// Kernel 1b: pack (col, val) into ONE dword.
//   bits[31:15] = col (100000 < 2^17), bits[14:0] = bf16(val) sans sign.
// ---------------------------------------------------------------------------
__global__ __launch_bounds__(256) void pack_edges4(const int* __restrict__ ecol,
                                                   const float* __restrict__ evalv,
                                                   unsigned* __restrict__ ep4) {
    int i = blockIdx.x * blockDim.x + threadIdx.x;
    if (i >= N_EDGES) return;
    unsigned bf = f32_to_bf16(evalv[i]);
    ep4[i] = ((unsigned)ecol[i] << 15) | (bf & 0x7fffu);
}

// ---------------------------------------------------------------------------
// Kernel 1d: per-row stable partition of edges by col < COL_SPLIT.
// One thread per row (deg ~16). Produces ep2 (reordered) + rs (split point).
// One-time cost; enables L2-resident gathers in each prop pass.
// ---------------------------------------------------------------------------
__global__ __launch_bounds__(256) void part_edges(const int* __restrict__ rp,
                                                  const unsigned* __restrict__ ep4,
                                                  unsigned* __restrict__ ep2,
                                                  int* __restrict__ rs) {
    int r = blockIdx.x * blockDim.x + threadIdx.x;
    if (r >= N_NODES) return;
    int e0 = rp[r], e1 = rp[r + 1];
    int cnt = 0;
    for (int e = e0; e < e1; ++e) cnt += ((ep4[e] >> 15) < COL_SPLIT);
    rs[r] = e0 + cnt;
    int plo = e0, phi = e0 + cnt;
    for (int e = e0; e < e1; ++e) {
        unsigned p = ep4[e];
        if ((p >> 15) < COL_SPLIT) ep2[plo++] = p;
        else                       ep2[phi++] = p;
    }
}

// ---------------------------------------------------------------------------
// Kernel 1c: W1 [256][64] fp32 -> W1T [64][256] bf16 (for MFMA B-fragments).
// ---------------------------------------------------------------------------
__global__ __launch_bounds__(256) void prep_w1t(const float* __restrict__ W1,
                                                unsigned short* __restrict__ W1T) {
    int i = blockIdx.x * 256 + threadIdx.x;           // 16384 elements
    if (i >= D_IN * D_HID) return;
    int k = i >> 6, n = i & 63;
    W1T[n * 256 + k] = f32_to_bf16(W1[i]);
}

// ---------------------------------------------------------------------------
// Kernel 2 (MFMA): h = x @ W1 + b1. EXACT R0 core (59.5 us known-good; it
// sits at the per-CU outstanding-line cap -> restructures are null, two
// attempts confirmed). Epilogue writes bf16 Y, bf16 src, fp8 Y8.
// ---------------------------------------------------------------------------
__global__ __launch_bounds__(64) void mlp1(const float* __restrict__ x,
                                           const unsigned short* __restrict__ W1T,
                                           const float* __restrict__ b1,
                                           const float* __restrict__ diag,
                                           unsigned short* __restrict__ Yb,
                                           unsigned char* __restrict__ Y08,
                                           unsigned short* __restrict__ srcb) {
    const int lane  = threadIdx.x;
    const int l15   = lane & 15;
    const int quad  = lane >> 4;
    const int mbase = blockIdx.x * 16;      // 6250 * 16 == 100000 exactly

    f32x4 acc[4] = {};
    const float* xrow = x + (size_t)(mbase + l15) * D_IN + quad * 8;

    #pragma unroll
    for (int ks = 0; ks < 8; ++ks) {
        float4 f0 = *(const float4*)(xrow + ks * 32);
        float4 f1 = *(const float4*)(xrow + ks * 32 + 4);
        union { short8 v; unsigned int u[4]; } a;
        a.u[0] = f32x2_to_bf16x2(f0.x, f0.y);
        a.u[1] = f32x2_to_bf16x2(f0.z, f0.w);
        a.u[2] = f32x2_to_bf16x2(f1.x, f1.y);
        a.u[3] = f32x2_to_bf16x2(f1.z, f1.w);

        #pragma unroll
        for (int ct = 0; ct < 4; ++ct) {
            short8 b = *(const short8*)(W1T + (ct * 16 + l15) * 256 + ks * 32 + quad * 8);
            acc[ct] = __builtin_amdgcn_mfma_f32_16x16x32_bf16(a.v, b, acc[ct], 0, 0, 0);
        }
    }

    float bias[4];
    #pragma unroll
    for (int ct = 0; ct < 4; ++ct) bias[ct] = b1[ct * 16 + l15];

    #pragma unroll
    for (int reg = 0; reg < 4; ++reg) {
        const int mr = mbase + quad * 4 + reg;
        const float dg = diag[mr];
        #pragma unroll
        for (int ct = 0; ct < 4; ++ct) {
            const int col = ct * 16 + l15;
            const float h = acc[ct][reg] + bias[ct];
            const size_t idx = (size_t)mr * 64 + col;
            Yb[idx]   = f32_to_bf16(h);
            srcb[idx] = f32_to_bf16(0.5f * dg * h);
            Y08[idx]  = f32_to_fp8(h);
        }
    }
}

// ---------------------------------------------------------------------------
// Kernel 3: HALF of one propagation step (by COLUMN half, not feature half —
// each edge processed exactly once per step, unlike the failed R3 split).
// mode 0: edges [rp,rs) -> gathers hit Y8 rows [0,50K) = first 3.2MB (L2-fit);
//         partial acc parked in fp32 tmp.
// mode 1: edges [rs,rp+1) -> gathers hit second 3.2MB; combine tmp + self +
//         src, write bf16 Y and fp8 Y8.
// Model: gather cost drops 13.9 -> 6.6 cyc/line/CU (calibrated from R3).
// 4 rows/wave, 16 lanes/row, lane owns 4 features. Dword ep loads (uint4 vs
// dword proven null in R2).
// ---------------------------------------------------------------------------
__global__ __launch_bounds__(256) void prop_pass(const unsigned char* __restrict__ Y8,
                                                 const unsigned* __restrict__ ep2,
                                                 const int* __restrict__ bptr,
                                                 const int* __restrict__ eptr,
                                                 float* __restrict__ tmp,
                                                 const unsigned short* __restrict__ Yb,
                                                 const unsigned short* __restrict__ srcb,
                                                 unsigned short* __restrict__ Ybo,
                                                 unsigned char* __restrict__ Yo8,
                                                 const int mode) {
    const int wid  = blockIdx.x * 4 + (threadIdx.x >> 6);   // 25000 waves
    const int lane = threadIdx.x & 63;
    const int g    = lane >> 4;         // row group 0..3
    const int fl   = lane & 15;         // feature-quad index
    const int row  = wid * 4 + g;       // exact: 100000 = 4 * 25000

    const int b0 = bptr[row];
    const int e1 = eptr[row];

    const size_t fb = (size_t)row * 64 + fl * 4;
    const unsigned char* Y8f = Y8 + fl * 4;

    float4 acc0 = make_float4(0.f, 0.f, 0.f, 0.f);
    float4 acc1 = acc0, acc2 = acc0, acc3 = acc0;

    int e = b0;
    for (; e + 8 <= e1; e += 8) {
        unsigned p0 = ep2[e + 0], p1 = ep2[e + 1], p2 = ep2[e + 2], p3 = ep2[e + 3];
        unsigned p4 = ep2[e + 4], p5 = ep2[e + 5], p6 = ep2[e + 6], p7 = ep2[e + 7];
        unsigned q0 = *(const unsigned*)(Y8f + ((size_t)(p0 >> 15) << 6));
        unsigned q1 = *(const unsigned*)(Y8f + ((size_t)(p1 >> 15) << 6));
        unsigned q2 = *(const unsigned*)(Y8f + ((size_t)(p2 >> 15) << 6));
        unsigned q3 = *(const unsigned*)(Y8f + ((size_t)(p3 >> 15) << 6));
        unsigned q4 = *(const unsigned*)(Y8f + ((size_t)(p4 >> 15) << 6));
        unsigned q5 = *(const unsigned*)(Y8f + ((size_t)(p5 >> 15) << 6));
        unsigned q6 = *(const unsigned*)(Y8f + ((size_t)(p6 >> 15) << 6));
        unsigned q7 = *(const unsigned*)(Y8f + ((size_t)(p7 >> 15) << 6));
        fma4(acc0, edge_val(p0), q0);
        fma4(acc1, edge_val(p1), q1);
        fma4(acc2, edge_val(p2), q2);
        fma4(acc3, edge_val(p3), q3);
        fma4(acc0, edge_val(p4), q4);
        fma4(acc1, edge_val(p5), q5);
        fma4(acc2, edge_val(p6), q6);
        fma4(acc3, edge_val(p7), q7);
    }
    if (e + 4 <= e1) {
        unsigned p0 = ep2[e + 0], p1 = ep2[e + 1], p2 = ep2[e + 2], p3 = ep2[e + 3];
        unsigned q0 = *(const unsigned*)(Y8f + ((size_t)(p0 >> 15) << 6));
        unsigned q1 = *(const unsigned*)(Y8f + ((size_t)(p1 >> 15) << 6));
        unsigned q2 = *(const unsigned*)(Y8f + ((size_t)(p2 >> 15) << 6));
        unsigned q3 = *(const unsigned*)(Y8f + ((size_t)(p3 >> 15) << 6));
        fma4(acc0, edge_val(p0), q0);
        fma4(acc1, edge_val(p1), q1);
        fma4(acc2, edge_val(p2), q2);
        fma4(acc3, edge_val(p3), q3);
        e += 4;
    }
    for (; e < e1; ++e) {
        unsigned p = ep2[e];
        unsigned q = *(const unsigned*)(Y8f + ((size_t)(p >> 15) << 6));
        fma4(acc0, edge_val(p), q);
    }

    float4 accs;
    accs.x = (acc0.x + acc1.x) + (acc2.x + acc3.x);
    accs.y = (acc0.y + acc1.y) + (acc2.y + acc3.y);
    accs.z = (acc0.z + acc1.z) + (acc2.z + acc3.z);
    accs.w = (acc0.w + acc1.w) + (acc2.w + acc3.w);

    if (mode == 0) {
        *(float4*)(tmp + fb) = accs;            // park partial (fp32: no rounding)
        return;
    }

    const float4 t = *(const float4*)(tmp + fb);
    accs.x += t.x; accs.y += t.y; accs.z += t.z; accs.w += t.w;

    const ushort4 ys4 = *(const ushort4*)(Yb + fb);
    const ushort4 sv4 = *(const ushort4*)(srcb + fb);

    float4 o;
    o.x = fmaf(0.5f, bf16_f(ys4.x), fmaf(0.5f, accs.x, bf16_f(sv4.x)));
    o.y = fmaf(0.5f, bf16_f(ys4.y), fmaf(0.5f, accs.y, bf16_f(sv4.y)));
    o.z = fmaf(0.5f, bf16_f(ys4.z), fmaf(0.5f, accs.z, bf16_f(sv4.z)));
    o.w = fmaf(0.5f, bf16_f(ys4.w), fmaf(0.5f, accs.w, bf16_f(sv4.w)));

    ushort4 ob;
    ob.x = f32_to_bf16(o.x); ob.y = f32_to_bf16(o.y);
    ob.z = f32_to_bf16(o.z); ob.w = f32_to_bf16(o.w);
    *(ushort4*)(Ybo + fb) = ob;
    int pk = __builtin_amdgcn_cvt_pk_fp8_f32(o.x, o.y, 0, false);   // bytes 0,1
    pk     = __builtin_amdgcn_cvt_pk_fp8_f32(o.z, o.w, pk, true);   // bytes 2,3
    *(unsigned*)(Yo8 + fb) = (unsigned)pk;
}

// ---------------------------------------------------------------------------
// Kernel 4: out = relu(Y) @ W2 + b2. Y bf16 (uint4 = 8 features/load).
// ---------------------------------------------------------------------------
__global__ __launch_bounds__(256) void mlp2(const unsigned short* __restrict__ Yb,
                                            const float* __restrict__ W2,
                                            const float* __restrict__ b2,
                                            float* __restrict__ out) {
    __shared__ float W2s[D_HID * D_OUT];
    __shared__ float b2s[D_OUT];
    int tid = threadIdx.x;
    for (int i = tid; i < D_HID * D_OUT; i += 256) W2s[i] = W2[i];
    if (tid < D_OUT) b2s[tid] = b2[tid];
    __syncthreads();

    int n = blockIdx.x * 256 + tid;
    if (n >= N_NODES) return;

    float acc[D_OUT];
    #pragma unroll
    for (int o = 0; o < D_OUT; ++o) acc[o] = b2s[o];

    const uint4* Y4 = (const uint4*)(Yb + (size_t)n * 64);
    #pragma unroll
    for (int k8 = 0; k8 < 8; ++k8) {
        uint4 y = Y4[k8];
        unsigned w[4] = {y.x, y.y, y.z, y.w};
        #pragma unroll
        for (int d = 0; d < 4; ++d) {
            float lo = fmaxf(__uint_as_float((w[d] & 0xffffu) << 16), 0.0f);
            float hi = fmaxf(__uint_as_float(w[d] & 0xffff0000u), 0.0f);
            int klo = k8 * 8 + 2 * d, khi = klo + 1;
            #pragma unroll
            for (int o = 0; o < D_OUT; ++o)
                acc[o] = fmaf(lo, W2s[klo * D_OUT + o], acc[o]);
            #pragma unroll
            for (int o = 0; o < D_OUT; ++o)
                acc[o] = fmaf(hi, W2s[khi * D_OUT + o], acc[o]);
        }
    }

    float4* o4 = (float4*)(out + (size_t)n * D_OUT);
    #pragma unroll
    for (int q = 0; q < 10; ++q)
        o4[q] = make_float4(acc[4 * q], acc[4 * q + 1], acc[4 * q + 2], acc[4 * q + 3]);
}

// ---------------------------------------------------------------------------
extern "C" void kernel_launch(void* const* d_in, const int* in_sizes, int n_in,
                              void* d_out, int out_size, void* d_ws, size_t ws_size,
                              hipStream_t stream) {
    const float* x     = (const float*)d_in[0];
    const int*   erow  = (const int*)  d_in[1];
    const int*   ecol  = (const int*)  d_in[2];
    const float* evalv = (const float*)d_in[3];
    const float* diag  = (const float*)d_in[4];
    const float* W1    = (const float*)d_in[5];
    const float* b1    = (const float*)d_in[6];
    const float* W2    = (const float*)d_in[7];
    const float* b2    = (const float*)d_in[8];
    float* out = (float*)d_out;

    // workspace: Yb0|Yb1|srcb (bf16) | Y08|Y18 (fp8) | tmp (fp32) |
    //            ep4 | ep2 | rp | rs | W1T
    const size_t NV = (size_t)N_NODES * D_HID;
    unsigned short* Yb0  = (unsigned short*)d_ws;
    unsigned short* Yb1  = Yb0 + NV;
    unsigned short* srcb = Yb1 + NV;
    unsigned char*  Y08  = (unsigned char*)(srcb + NV);
    unsigned char*  Y18  = Y08 + NV;
    float*          tmp  = (float*)(Y18 + NV);
    unsigned*       ep4  = (unsigned*)(tmp + NV);
    unsigned*       ep2  = ep4 + N_EDGES;
    int*            rp   = (int*)(ep2 + N_EDGES);
    int*            rs   = rp + (N_NODES + 1);
    unsigned short* W1T  = (unsigned short*)
        (((unsigned long long)(rs + N_NODES) + 15ull) & ~15ull);

    build_rowptr<<<(N_NODES + 1 + 255) / 256, 256, 0, stream>>>(erow, rp);
    pack_edges4<<<(N_EDGES + 255) / 256, 256, 0, stream>>>(ecol, evalv, ep4);
    part_edges<<<(N_NODES + 255) / 256, 256, 0, stream>>>(rp, ep4, ep2, rs);
    prep_w1t<<<(D_IN * D_HID + 255) / 256, 256, 0, stream>>>(W1, W1T);
    mlp1<<<N_NODES / 16, 64, 0, stream>>>(x, W1T, b1, diag, Yb0, Y08, srcb);

    unsigned short* Yb[2] = {Yb0, Yb1};
    unsigned char*  Y8[2] = {Y08, Y18};
    for (int i = 0; i < PROP_N; ++i) {
        const int c = i & 1, n = (i + 1) & 1;
        // pass A: lo-col edges -> Y8 rows [0,50K) (first 3.2MB, L2-resident)
        prop_pass<<<N_NODES / 16, 256, 0, stream>>>(
            Y8[c], ep2, rp, rs, tmp, nullptr, nullptr, nullptr, nullptr, 0);
        // pass B: hi-col edges -> Y8 rows [50K,100K); combine + write outputs
        prop_pass<<<N_NODES / 16, 256, 0, stream>>>(
            Y8[c], ep2, rs, rp + 1, tmp, Yb[c], srcb, Yb[n], Y8[n], 1);
    }
    // PROP_N even -> final bf16 result in Yb0
    mlp2<<<(N_NODES + 255) / 256, 256, 0, stream>>>(Yb0, W2, b2, out);
}

// Round 6
// 755.977 us; speedup vs baseline: 1.2269x; 1.2269x over previous
//
#include <hip/hip_runtime.h>

#define N_NODES 100000
#define N_EDGES 1600000
#define D_IN    256
#define D_HID   64
#define D_OUT   40
#define PROP_N  16

typedef short short8 __attribute__((ext_vector_type(8)));   // 8 bf16 (4 VGPRs)
typedef float f32x4  __attribute__((ext_vector_type(4)));   // MFMA accumulator

// ---- fp8 (OCP e4m3) helpers: HW convert, RNE, saturating ------------------
__device__ __forceinline__ unsigned char f32_to_fp8(float f) {
    int p = __builtin_amdgcn_cvt_pk_fp8_f32(f, f, 0, false);
    return (unsigned char)(p & 0xff);
}
// ---- bf16 helpers (RNE) ---------------------------------------------------
__device__ __forceinline__ unsigned short f32_to_bf16(float f) {
    unsigned int u = __float_as_uint(f);
    unsigned int r = (u + 0x7fffu + ((u >> 16) & 1u)) >> 16;
    return (unsigned short)r;
}
__device__ __forceinline__ unsigned int f32x2_to_bf16x2(float lo, float hi) {
    return (unsigned int)f32_to_bf16(lo) | ((unsigned int)f32_to_bf16(hi) << 16);
}
__device__ __forceinline__ float bf16_f(unsigned short u) {
    return __uint_as_float(((unsigned)u) << 16);
}
// decode packed edge: bits[31:15]=col, bits[14:0]=bf16(val) without sign
__device__ __forceinline__ float edge_val(unsigned p) {
    return __uint_as_float((p & 0x7fffu) << 16);
}
// 4-feature fp8 FMA: b holds 4 fp8 bytes
__device__ __forceinline__ void fma4(float4& a, float v, unsigned b) {
    a.x = fmaf(v, __builtin_amdgcn_cvt_f32_fp8((int)b, 0), a.x);
    a.y = fmaf(v, __builtin_amdgcn_cvt_f32_fp8((int)b, 1), a.y);
    a.z = fmaf(v, __builtin_amdgcn_cvt_f32_fp8((int)b, 2), a.z);
    a.w = fmaf(v, __builtin_amdgcn_cvt_f32_fp8((int)b, 3), a.w);
}
// async global->LDS DMA: 16B per lane, dest = uniform base + lane*16 (HW)
__device__ __forceinline__ void gload16(const void* g, void* l) {
    __builtin_amdgcn_global_load_lds(
        (__attribute__((address_space(1))) void*)g,
        (__attribute__((address_space(3))) void*)l, 16, 0, 0);
}

// ---------------------------------------------------------------------------
// Kernel 1: CSR row_ptr from sorted edge_row via binary search.
// ---------------------------------------------------------------------------
__global__ __launch_bounds__(256) void build_rowptr(const int* __restrict__ erow,
                                                    int* __restrict__ rp) {
    int r = blockIdx.x * blockDim.x + threadIdx.x;
    if (r > N_NODES) return;
    int lo = 0, hi = N_EDGES;
    while (lo < hi) {
        int mid = (lo + hi) >> 1;
        if (erow[mid] < r) lo = mid + 1; else hi = mid;
    }
    rp[r] = lo;
}

// ---------------------------------------------------------------------------
// Kernel 1b: pack (col, val) into ONE dword.
//   bits[31:15] = col (100000 < 2^17), bits[14:0] = bf16(val) sans sign.
// ---------------------------------------------------------------------------
__global__ __launch_bounds__(256) void pack_edges4(const int* __restrict__ ecol,
                                                   const float* __restrict__ evalv,
                                                   unsigned* __restrict__ ep4) {
    int i = blockIdx.x * blockDim.x + threadIdx.x;
    if (i >= N_EDGES) return;
    unsigned bf = f32_to_bf16(evalv[i]);
    ep4[i] = ((unsigned)ecol[i] << 15) | (bf & 0x7fffu);
}

// ---------------------------------------------------------------------------
// Kernel 1c: W1 [256][64] fp32 -> W1T [64][256] bf16 (for MFMA B-fragments).
// ---------------------------------------------------------------------------
__global__ __launch_bounds__(256) void prep_w1t(const float* __restrict__ W1,
                                                unsigned short* __restrict__ W1T) {
    int i = blockIdx.x * 256 + threadIdx.x;           // 16384 elements
    if (i >= D_IN * D_HID) return;
    int k = i >> 6, n = i & 63;
    W1T[n * 256 + k] = f32_to_bf16(W1[i]);
}

// ---------------------------------------------------------------------------
// Kernel 2 (MFMA): h = x @ W1 + b1 ; Yb/srcb (bf16), Y8 (fp8).
// CHANGE vs R4/R5: x staged via ASYNC global_load_lds (16B/lane, 1KB/row per
// instruction). 32 rows/block (128 thr), 32KB LDS, all 32 row-loads issued
// before the barrier -> hundreds of lines in flight per CU (prev: sync loads,
// ~2-4/wave => 1.7TB/s, 22% HBM, everything idle). LDS XOR-swizzle
// (byte ^= (row&7)<<4) applied by pre-swizzling the GLOBAL source (m173:
// gload_lds dest must stay linear); fragment ds_read_b128 then lands uniform
// 8 dwords/bank. Numerics bit-identical to R4 mlp1.
// ---------------------------------------------------------------------------
__global__ __launch_bounds__(128) void mlp1(const float* __restrict__ x,
                                            const unsigned short* __restrict__ W1T,
                                            const float* __restrict__ b1,
                                            const float* __restrict__ diag,
                                            unsigned short* __restrict__ Yb,
                                            unsigned char* __restrict__ Y08,
                                            unsigned short* __restrict__ srcb) {
    __shared__ __align__(16) char tile[32 * 1024];    // 32 rows x 1KB

    const int tid   = threadIdx.x;
    const int wslot = tid >> 6;             // wave 0/1
    const int lane  = tid & 63;
    const int l15   = lane & 15;
    const int quad  = lane >> 4;
    const int mbase = blockIdx.x * 32;      // 3125 * 32 == 100000 exactly

    // ---- async stage: wave w loads rows w*16..w*16+15 (one instr per row)
    #pragma unroll
    for (int i = 0; i < 16; ++i) {
        const int rr = wslot * 16 + i;
        const char* gp = (const char*)x + (size_t)(mbase + rr) * 1024
                       + ((lane * 16) ^ ((rr & 7) << 4));
        gload16(gp, tile + rr * 1024);
    }
    __syncthreads();   // compiler drains vmcnt(0) before s_barrier

    // ---- compute: wave w owns rows w*16 + l15
    const int rr = wslot * 16 + l15;
    const char* lrow = tile + rr * 1024;
    const int sw = (l15 & 7) << 4;

    f32x4 acc[4] = {};
    #pragma unroll
    for (int ks = 0; ks < 8; ++ks) {
        const int off = quad * 32 + ks * 128;
        float4 f0 = *(const float4*)(lrow + ((off)      ^ sw));
        float4 f1 = *(const float4*)(lrow + ((off + 16) ^ sw));
        union { short8 v; unsigned int u[4]; } a;
        a.u[0] = f32x2_to_bf16x2(f0.x, f0.y);
        a.u[1] = f32x2_to_bf16x2(f0.z, f0.w);
        a.u[2] = f32x2_to_bf16x2(f1.x, f1.y);
        a.u[3] = f32x2_to_bf16x2(f1.z, f1.w);

        #pragma unroll
        for (int ct = 0; ct < 4; ++ct) {
            short8 b = *(const short8*)(W1T + (ct * 16 + l15) * 256 + ks * 32 + quad * 8);
            acc[ct] = __builtin_amdgcn_mfma_f32_16x16x32_bf16(a.v, b, acc[ct], 0, 0, 0);
        }
    }

    float bias[4];
    #pragma unroll
    for (int ct = 0; ct < 4; ++ct) bias[ct] = b1[ct * 16 + l15];

    const int mrow0 = mbase + wslot * 16;
    #pragma unroll
    for (int reg = 0; reg < 4; ++reg) {
        const int mr = mrow0 + quad * 4 + reg;
        const float dg = diag[mr];
        #pragma unroll
        for (int ct = 0; ct < 4; ++ct) {
            const int col = ct * 16 + l15;
            const float h = acc[ct][reg] + bias[ct];
            const size_t idx = (size_t)mr * 64 + col;
            Yb[idx]   = f32_to_bf16(h);
            srcb[idx] = f32_to_bf16(0.5f * dg * h);
            Y08[idx]  = f32_to_fp8(h);
        }
    }
}

// ---------------------------------------------------------------------------
// Kernel 3: one propagation step. EXACT R4 structure (42 us/step known-best).
// R3 (feature-split) and R5 (column-split) both regressed: added stream
// traffic to buy gather residency loses. bf16 self/src/out streams.
// ---------------------------------------------------------------------------
__global__ __launch_bounds__(256) void prop_step(const unsigned short* __restrict__ Yb,
                                                 const unsigned char* __restrict__ Y8,
                                                 const unsigned short* __restrict__ srcb,
                                                 unsigned short* __restrict__ Ybo,
                                                 unsigned char* __restrict__ Yo8,
                                                 const int* __restrict__ rp,
                                                 const unsigned* __restrict__ ep4) {
    const int wid  = blockIdx.x * 4 + (threadIdx.x >> 6);   // 25000 waves
    const int lane = threadIdx.x & 63;
    const int g    = lane >> 4;         // row group 0..3
    const int fl   = lane & 15;         // feature-quad index
    const int row  = wid * 4 + g;       // exact: 100000 = 4 * 25000

    const int e0 = rp[row];
    const int e1 = rp[row + 1];

    const size_t fb = (size_t)row * 64 + fl * 4;
    const ushort4 ys4 = *(const ushort4*)(Yb + fb);
    const ushort4 sv4 = *(const ushort4*)(srcb + fb);
    const float4 yself = make_float4(bf16_f(ys4.x), bf16_f(ys4.y),
                                     bf16_f(ys4.z), bf16_f(ys4.w));
    const float4 sv    = make_float4(bf16_f(sv4.x), bf16_f(sv4.y),
                                     bf16_f(sv4.z), bf16_f(sv4.w));
    const unsigned char* Y8f = Y8 + fl * 4;

    float4 acc0 = make_float4(0.f, 0.f, 0.f, 0.f);
    float4 acc1 = acc0, acc2 = acc0, acc3 = acc0;

    int e = e0;
    // scalar head until e is 4-aligned (16B-aligned uint4 loads)
    int ea = (e0 + 3) & ~3;
    if (ea > e1) ea = e1;
    for (; e < ea; ++e) {
        unsigned p = ep4[e];
        unsigned b = *(const unsigned*)(Y8f + ((size_t)(p >> 15) << 6));
        fma4(acc0, edge_val(p), b);
    }
    for (; e + 8 <= e1; e += 8) {
        uint4 pa = *(const uint4*)(ep4 + e);
        uint4 pb = *(const uint4*)(ep4 + e + 4);
        unsigned b0 = *(const unsigned*)(Y8f + ((size_t)(pa.x >> 15) << 6));
        unsigned b1 = *(const unsigned*)(Y8f + ((size_t)(pa.y >> 15) << 6));
        unsigned b2 = *(const unsigned*)(Y8f + ((size_t)(pa.z >> 15) << 6));
        unsigned b3 = *(const unsigned*)(Y8f + ((size_t)(pa.w >> 15) << 6));
        unsigned b4 = *(const unsigned*)(Y8f + ((size_t)(pb.x >> 15) << 6));
        unsigned b5 = *(const unsigned*)(Y8f + ((size_t)(pb.y >> 15) << 6));
        unsigned b6 = *(const unsigned*)(Y8f + ((size_t)(pb.z >> 15) << 6));
        unsigned b7 = *(const unsigned*)(Y8f + ((size_t)(pb.w >> 15) << 6));
        fma4(acc0, edge_val(pa.x), b0);
        fma4(acc1, edge_val(pa.y), b1);
        fma4(acc2, edge_val(pa.z), b2);
        fma4(acc3, edge_val(pa.w), b3);
        fma4(acc0, edge_val(pb.x), b4);
        fma4(acc1, edge_val(pb.y), b5);
        fma4(acc2, edge_val(pb.z), b6);
        fma4(acc3, edge_val(pb.w), b7);
    }
    if (e + 4 <= e1) {
        uint4 pa = *(const uint4*)(ep4 + e);
        unsigned b0 = *(const unsigned*)(Y8f + ((size_t)(pa.x >> 15) << 6));
        unsigned b1 = *(const unsigned*)(Y8f + ((size_t)(pa.y >> 15) << 6));
        unsigned b2 = *(const unsigned*)(Y8f + ((size_t)(pa.z >> 15) << 6));
        unsigned b3 = *(const unsigned*)(Y8f + ((size_t)(pa.w >> 15) << 6));
        fma4(acc0, edge_val(pa.x), b0);
        fma4(acc1, edge_val(pa.y), b1);
        fma4(acc2, edge_val(pa.z), b2);
        fma4(acc3, edge_val(pa.w), b3);
        e += 4;
    }
    for (; e < e1; ++e) {
        unsigned p = ep4[e];
        unsigned b = *(const unsigned*)(Y8f + ((size_t)(p >> 15) << 6));
        fma4(acc0, edge_val(p), b);
    }

    float4 accs;
    accs.x = (acc0.x + acc1.x) + (acc2.x + acc3.x);
    accs.y = (acc0.y + acc1.y) + (acc2.y + acc3.y);
    accs.z = (acc0.z + acc1.z) + (acc2.z + acc3.z);
    accs.w = (acc0.w + acc1.w) + (acc2.w + acc3.w);

    float4 o;
    o.x = fmaf(0.5f, yself.x, fmaf(0.5f, accs.x, sv.x));
    o.y = fmaf(0.5f, yself.y, fmaf(0.5f, accs.y, sv.y));
    o.z = fmaf(0.5f, yself.z, fmaf(0.5f, accs.z, sv.z));
    o.w = fmaf(0.5f, yself.w, fmaf(0.5f, accs.w, sv.w));

    ushort4 ob;
    ob.x = f32_to_bf16(o.x); ob.y = f32_to_bf16(o.y);
    ob.z = f32_to_bf16(o.z); ob.w = f32_to_bf16(o.w);
    *(ushort4*)(Ybo + fb) = ob;
    int pk = __builtin_amdgcn_cvt_pk_fp8_f32(o.x, o.y, 0, false);   // bytes 0,1
    pk     = __builtin_amdgcn_cvt_pk_fp8_f32(o.z, o.w, pk, true);   // bytes 2,3
    *(unsigned*)(Yo8 + fb) = (unsigned)pk;
}

// ---------------------------------------------------------------------------
// Kernel 4: out = relu(Y) @ W2 + b2. Y bf16 (uint4 = 8 features/load).
// ---------------------------------------------------------------------------
__global__ __launch_bounds__(256) void mlp2(const unsigned short* __restrict__ Yb,
                                            const float* __restrict__ W2,
                                            const float* __restrict__ b2,
                                            float* __restrict__ out) {
    __shared__ float W2s[D_HID * D_OUT];
    __shared__ float b2s[D_OUT];
    int tid = threadIdx.x;
    for (int i = tid; i < D_HID * D_OUT; i += 256) W2s[i] = W2[i];
    if (tid < D_OUT) b2s[tid] = b2[tid];
    __syncthreads();

    int n = blockIdx.x * 256 + tid;
    if (n >= N_NODES) return;

    float acc[D_OUT];
    #pragma unroll
    for (int o = 0; o < D_OUT; ++o) acc[o] = b2s[o];

    const uint4* Y4 = (const uint4*)(Yb + (size_t)n * 64);
    #pragma unroll
    for (int k8 = 0; k8 < 8; ++k8) {
        uint4 y = Y4[k8];
        unsigned w[4] = {y.x, y.y, y.z, y.w};
        #pragma unroll
        for (int d = 0; d < 4; ++d) {
            float lo = fmaxf(__uint_as_float((w[d] & 0xffffu) << 16), 0.0f);
            float hi = fmaxf(__uint_as_float(w[d] & 0xffff0000u), 0.0f);
            int klo = k8 * 8 + 2 * d, khi = klo + 1;
            #pragma unroll
            for (int o = 0; o < D_OUT; ++o)
                acc[o] = fmaf(lo, W2s[klo * D_OUT + o], acc[o]);
            #pragma unroll
            for (int o = 0; o < D_OUT; ++o)
                acc[o] = fmaf(hi, W2s[khi * D_OUT + o], acc[o]);
        }
    }

    float4* o4 = (float4*)(out + (size_t)n * D_OUT);
    #pragma unroll
    for (int q = 0; q < 10; ++q)
        o4[q] = make_float4(acc[4 * q], acc[4 * q + 1], acc[4 * q + 2], acc[4 * q + 3]);
}

// ---------------------------------------------------------------------------
extern "C" void kernel_launch(void* const* d_in, const int* in_sizes, int n_in,
                              void* d_out, int out_size, void* d_ws, size_t ws_size,
                              hipStream_t stream) {
    const float* x     = (const float*)d_in[0];
    const int*   erow  = (const int*)  d_in[1];
    const int*   ecol  = (const int*)  d_in[2];
    const float* evalv = (const float*)d_in[3];
    const float* diag  = (const float*)d_in[4];
    const float* W1    = (const float*)d_in[5];
    const float* b1    = (const float*)d_in[6];
    const float* W2    = (const float*)d_in[7];
    const float* b2    = (const float*)d_in[8];
    float* out = (float*)d_out;

    // workspace: Yb0|Yb1|srcb (bf16) | Y08|Y18 (fp8) | ep4 | rp | W1T
    const size_t NV = (size_t)N_NODES * D_HID;
    unsigned short* Yb0  = (unsigned short*)d_ws;
    unsigned short* Yb1  = Yb0 + NV;
    unsigned short* srcb = Yb1 + NV;
    unsigned char*  Y08  = (unsigned char*)(srcb + NV);
    unsigned char*  Y18  = Y08 + NV;
    unsigned*       ep4  = (unsigned*)(Y18 + NV);
    int*            rp   = (int*)(ep4 + N_EDGES);
    unsigned short* W1T  = (unsigned short*)
        (((unsigned long long)(rp + N_NODES + 1) + 15ull) & ~15ull);

    build_rowptr<<<(N_NODES + 1 + 255) / 256, 256, 0, stream>>>(erow, rp);
    pack_edges4<<<(N_EDGES + 255) / 256, 256, 0, stream>>>(ecol, evalv, ep4);
    prep_w1t<<<(D_IN * D_HID + 255) / 256, 256, 0, stream>>>(W1, W1T);
    mlp1<<<N_NODES / 32, 128, 0, stream>>>(x, W1T, b1, diag, Yb0, Y08, srcb);

    unsigned short* Yb[2] = {Yb0, Yb1};
    unsigned char*  Y8[2] = {Y08, Y18};
    for (int i = 0; i < PROP_N; ++i) {
        prop_step<<<N_NODES / 16, 256, 0, stream>>>(
            Yb[i & 1], Y8[i & 1], srcb, Yb[(i + 1) & 1], Y8[(i + 1) & 1], rp, ep4);
    }
    // PROP_N even -> final bf16 result in Yb0
    mlp2<<<(N_NODES + 255) / 256, 256, 0, stream>>>(Yb0, W2, b2, out);
}